// Round 7
// baseline (135.439 us; speedup 1.0000x reference)
//
#include <hip/hip_runtime.h>
#include <hip/hip_bf16.h>

// FlowNet correlation via bf16 MFMA (gfx950).
// out[b, p*9+o, y, x] = (1/128) sum_c f[b,c,y,x] * s[b,c,y+p-4,x+o-4], zero-pad.
//
// Banded-GEMM: per (b,y,p) OUT[x,x'] = sum_c F[x,c] S[c,x'], keep |x'-x|<=4.
// Block = (b, 4y, 32x). 16 waves = (yslot 0..3) x (mn 0..3: M0N0,M0N1,M1N1,M1N2).
// Round 7: staging rewritten — unit = (row, x-quad, channel-octet): 8 float4
// loads -> 16 v_cvt_pk_bf16_f32 (via __float22bfloat162_rn; round 6 hand-rolled
// RTNE = 3-4 VALU/elem on the barrier-critical path) -> 4 ds_write_b128.
// 704 units, <=1 per thread. Prefetch issued before first barrier of the chunk.

namespace {
constexpr int kC = 128, kH = 128, kW = 256;
constexpr int kWin = 9;
constexpr int kYB = 4, kXB = 32;
constexpr int kSR = kYB + 8;                      // 12 s-rows
constexpr int kSX = kXB + 16;                     // 48 s-cols (x' span)
constexpr int kCP = 40;                           // padded c-stride (entries)
constexpr int kKC = 32;                           // channels per chunk
constexpr int kNK = kC / kKC;                     // 4
constexpr int kSSz = kSR * kSX * kCP;             // 23040 entries
constexpr int kFSz = kYB * kXB * kCP;             // 5120
constexpr int kBufSz = kSSz + kFSz;               // 28160 entries = 56320 B
constexpr int kSU = kSR * (kSX / 4) * (kKC / 8);  // 576 staging units
constexpr int kFU = kYB * (kXB / 4) * (kKC / 8);  // 128
constexpr int kTU = kSU + kFU;                    // 704 (<= 1024, 1/thread)
constexpr int kThreads = 1024;
constexpr int kBlocks = 4 * (kH / kYB) * (kW / kXB);  // 1024
constexpr int kOS = 132;                          // OUT_lds per-d stride (words)
constexpr int kCStr = kH * kW;                    // 32768

typedef __attribute__((ext_vector_type(8))) short bf16x8;
typedef __attribute__((ext_vector_type(4))) float f32x4;
}  // namespace

__global__ __launch_bounds__(kThreads, 8) void corr_mfma(
    const float* __restrict__ first,
    const float* __restrict__ second,
    float* __restrict__ out)
{
    __shared__ __align__(16) unsigned short lds[kBufSz];   // 56.3 KB

    const int tid  = threadIdx.x;
    const int lane = tid & 63;
    const int wid  = tid >> 6;          // 0..15
    const int yslot = wid >> 2;         // 0..3
    const int mn    = wid & 3;          // 0:M0N0 1:M0N1 2:M1N1 3:M1N2

    // XCD-aware bijective swizzle (1024 = 8 x 128)
    int bid = blockIdx.x;
    bid = (bid & 7) * (kBlocks / 8) + (bid >> 3);
    const int b   = bid >> 8;
    const int rem = bid & 255;
    const int y0  = (rem >> 3) * kYB;
    const int X0  = (rem & 7) * kXB;

    // ---- staging role: ONE unit per thread (tid < 704) ----
    // unit = (row, x-quad, channel-octet): 8 float4 loads (c..c+7 planes),
    // 16 cvt_pk, 4 ds_write_b128 into [x][c] layout.
    const float* ug = nullptr;   // global base (channel co*8, this row, x-quad)
    int ul = -1;                 // LDS entry offset of (x-quad start, c-octet)
    if (tid < kSU) {
        int co = tid & 3, xq = (tid >> 2) % 12, row = tid / 48;
        int yg = y0 - 4 + row, xg = X0 - 8 + xq * 4;
        ul = (row * kSX + xq * 4) * kCP + co * 8;
        if (yg >= 0 && yg < kH && xg >= 0 && xg <= kW - 4)
            ug = second + ((size_t)(b * kC + co * 8) * kH + yg) * kW + xg;
    } else if (tid < kTU) {
        int u2 = tid - kSU;
        int co = u2 & 3, xq = (u2 >> 2) & 7, row = u2 >> 5;
        ul = kSSz + (row * kXB + xq * 4) * kCP + co * 8;
        ug = first + ((size_t)(b * kC + co * 8) * kH + (y0 + row)) * kW
                   + (X0 + xq * 4);
    }

    float4 pv[8];
    auto issue = [&](int kc) {
        if (ul < 0) return;
        const float4 z = make_float4(0.f, 0.f, 0.f, 0.f);
#pragma unroll
        for (int j = 0; j < 8; ++j) pv[j] = z;
        if (ug) {
            const float* g = ug + (size_t)kc * kKC * kCStr;
#pragma unroll
            for (int j = 0; j < 8; ++j)
                pv[j] = *(const float4*)(g + (size_t)j * kCStr);
        }
    };
    auto write_lds = [&]() {
        if (ul < 0) return;
#pragma unroll
        for (int xi = 0; xi < 4; ++xi) {
            union { uint4 q; __hip_bfloat162 h[4]; } pk;
#pragma unroll
            for (int jj = 0; jj < 4; ++jj) {
                float lo = ((const float*)&pv[2 * jj])[xi];
                float hi = ((const float*)&pv[2 * jj + 1])[xi];
                pk.h[jj] = __float22bfloat162_rn(make_float2(lo, hi));
            }
            *(uint4*)&lds[ul + xi * kCP] = pk.q;
        }
    };

    // ---- compute-side fragment offsets (constant across k-chunks) ----
    const int l15 = lane & 15, lg = lane >> 4;
    const int Ms = mn >> 1, Ns = (mn + 1) >> 1;
    const int aoff = kSSz + (yslot * kXB + Ms * 16 + l15) * kCP + lg * 8;
    const int boff = (yslot * kSX + Ns * 16 + l15) * kCP + lg * 8;

    f32x4 acc[kWin];
    {
        f32x4 z = {0.f, 0.f, 0.f, 0.f};
#pragma unroll
        for (int p = 0; p < kWin; ++p) acc[p] = z;
    }

    // ---- K loop: write(kc) -> issue(kc+1) -> sync -> compute(kc) -> sync ----
    issue(0);
    for (int kc = 0; kc < kNK; ++kc) {
        write_lds();
        if (kc < kNK - 1) issue(kc + 1);
        __syncthreads();
        bf16x8 a = *(const bf16x8*)&lds[aoff];
#pragma unroll
        for (int p = 0; p < kWin; ++p) {
            bf16x8 bb = *(const bf16x8*)&lds[boff + p * (kSX * kCP)];
            acc[p] = __builtin_amdgcn_mfma_f32_16x16x32_bf16(a, bb, acc[p], 0, 0, 0);
        }
        __syncthreads();
    }

    // ---- epilogue: band-extract into OUT_lds, then coalesced stores ----
    float* outb = (float*)lds;
    const float inv = 1.0f / (float)kC;
    const int delta = (mn & 1) ? 12 : -4;      // (Xn - Xm) + 4
#pragma unroll
    for (int p = 0; p < kWin; ++p) {
#pragma unroll
        for (int r = 0; r < 4; ++r) {
            int m = (lg << 2) + r;
            int o = l15 - m + delta;
            if (o >= 0 && o < kWin) {
                int d = p * kWin + o;
                outb[d * kOS + yslot * kXB + Ms * 16 + m] = acc[p][r] * inv;
            }
        }
    }
    __syncthreads();

    const size_t ob = (size_t)b * (kWin * kWin) * kCStr;
    for (int i = tid; i < kWin * kWin * kYB * (kXB / 4); i += kThreads) {
        int d = i >> 5;                 // 32 float4 per d (4y x 8xq)
        int r2 = i & 31;
        int yy = r2 >> 3, xq = r2 & 7;
        float4 v = *(const float4*)&outb[d * kOS + yy * kXB + xq * 4];
        *(float4*)&out[ob + ((size_t)d * kH + (y0 + yy)) * kW + X0 + xq * 4] = v;
    }
}

extern "C" void kernel_launch(void* const* d_in, const int* in_sizes, int n_in,
                              void* d_out, int out_size, void* d_ws, size_t ws_size,
                              hipStream_t stream) {
    const float* first  = (const float*)d_in[0];
    const float* second = (const float*)d_in[1];
    float* out = (float*)d_out;
    dim3 grid(kBlocks);      // 1024 blocks
    dim3 block(kThreads);    // 1024 threads = 16 waves
    hipLaunchKernelGGL(corr_mfma, grid, block, 0, stream, first, second, out);
}

// Round 8
// 63.067 us; speedup vs baseline: 2.1476x; 2.1476x over previous
//
#include <hip/hip_runtime.h>
#include <hip/hip_bf16.h>

// FlowNet correlation via bf16 MFMA (gfx950).
// out[b, p*9+o, y, x] = (1/128) sum_c f[b,c,y,x] * s[b,c,y+p-4,x+o-4], zero-pad.
//
// Banded-GEMM: per (b,y,p) OUT[x,x'] = sum_c F[x,c] S[c,x'], keep |x'-x|<=4.
// Block = (b, 4y, 32x). 16 waves = (yslot 0..3) x (mn 0..3: M0N0,M0N1,M1N1,M1N2).
// Round 8 = round 7 staging (unit = row x x-quad x channel-octet: 8 float4
// loads -> 16 v_cvt_pk_bf16_f32 -> 4 ds_write_b128) WITHOUT the min-waves
// launch bound. Round 7's __launch_bounds__(1024,8) forced VGPR=32 -> pv+acc
// spilled (WRITE_SIZE 42->378 MB, dur 68->135us). Lesson: never bound waves
// below the natural register footprint.

namespace {
constexpr int kC = 128, kH = 128, kW = 256;
constexpr int kWin = 9;
constexpr int kYB = 4, kXB = 32;
constexpr int kSR = kYB + 8;                      // 12 s-rows
constexpr int kSX = kXB + 16;                     // 48 s-cols (x' span)
constexpr int kCP = 40;                           // padded c-stride (entries)
constexpr int kKC = 32;                           // channels per chunk
constexpr int kNK = kC / kKC;                     // 4
constexpr int kSSz = kSR * kSX * kCP;             // 23040 entries
constexpr int kFSz = kYB * kXB * kCP;             // 5120
constexpr int kBufSz = kSSz + kFSz;               // 28160 entries = 56320 B
constexpr int kSU = kSR * (kSX / 4) * (kKC / 8);  // 576 staging units
constexpr int kFU = kYB * (kXB / 4) * (kKC / 8);  // 128
constexpr int kTU = kSU + kFU;                    // 704 (<= 1024, 1/thread)
constexpr int kThreads = 1024;
constexpr int kBlocks = 4 * (kH / kYB) * (kW / kXB);  // 1024
constexpr int kOS = 132;                          // OUT_lds per-d stride (words)
constexpr int kCStr = kH * kW;                    // 32768

typedef __attribute__((ext_vector_type(8))) short bf16x8;
typedef __attribute__((ext_vector_type(4))) float f32x4;
}  // namespace

__global__ __launch_bounds__(kThreads) void corr_mfma(
    const float* __restrict__ first,
    const float* __restrict__ second,
    float* __restrict__ out)
{
    __shared__ __align__(16) unsigned short lds[kBufSz];   // 56.3 KB

    const int tid  = threadIdx.x;
    const int lane = tid & 63;
    const int wid  = tid >> 6;          // 0..15
    const int yslot = wid >> 2;         // 0..3
    const int mn    = wid & 3;          // 0:M0N0 1:M0N1 2:M1N1 3:M1N2

    // XCD-aware bijective swizzle (1024 = 8 x 128)
    int bid = blockIdx.x;
    bid = (bid & 7) * (kBlocks / 8) + (bid >> 3);
    const int b   = bid >> 8;
    const int rem = bid & 255;
    const int y0  = (rem >> 3) * kYB;
    const int X0  = (rem & 7) * kXB;

    // ---- staging role: ONE unit per thread (tid < 704) ----
    const float* ug = nullptr;
    int ul = -1;
    if (tid < kSU) {
        int co = tid & 3, xq = (tid >> 2) % 12, row = tid / 48;
        int yg = y0 - 4 + row, xg = X0 - 8 + xq * 4;
        ul = (row * kSX + xq * 4) * kCP + co * 8;
        if (yg >= 0 && yg < kH && xg >= 0 && xg <= kW - 4)
            ug = second + ((size_t)(b * kC + co * 8) * kH + yg) * kW + xg;
    } else if (tid < kTU) {
        int u2 = tid - kSU;
        int co = u2 & 3, xq = (u2 >> 2) & 7, row = u2 >> 5;
        ul = kSSz + (row * kXB + xq * 4) * kCP + co * 8;
        ug = first + ((size_t)(b * kC + co * 8) * kH + (y0 + row)) * kW
                   + (X0 + xq * 4);
    }

    float4 pv[8];
    auto issue = [&](int kc) {
        if (ul < 0) return;
        const float4 z = make_float4(0.f, 0.f, 0.f, 0.f);
#pragma unroll
        for (int j = 0; j < 8; ++j) pv[j] = z;
        if (ug) {
            const float* g = ug + (size_t)kc * kKC * kCStr;
#pragma unroll
            for (int j = 0; j < 8; ++j)
                pv[j] = *(const float4*)(g + (size_t)j * kCStr);
        }
    };
    auto write_lds = [&]() {
        if (ul < 0) return;
#pragma unroll
        for (int xi = 0; xi < 4; ++xi) {
            union { uint4 q; __hip_bfloat162 h[4]; } pk;
#pragma unroll
            for (int jj = 0; jj < 4; ++jj) {
                float lo = ((const float*)&pv[2 * jj])[xi];
                float hi = ((const float*)&pv[2 * jj + 1])[xi];
                pk.h[jj] = __float22bfloat162_rn(make_float2(lo, hi));
            }
            *(uint4*)&lds[ul + xi * kCP] = pk.q;
        }
    };

    // ---- compute-side fragment offsets (constant across k-chunks) ----
    const int l15 = lane & 15, lg = lane >> 4;
    const int Ms = mn >> 1, Ns = (mn + 1) >> 1;
    const int aoff = kSSz + (yslot * kXB + Ms * 16 + l15) * kCP + lg * 8;
    const int boff = (yslot * kSX + Ns * 16 + l15) * kCP + lg * 8;

    f32x4 acc[kWin];
    {
        f32x4 z = {0.f, 0.f, 0.f, 0.f};
#pragma unroll
        for (int p = 0; p < kWin; ++p) acc[p] = z;
    }

    // ---- K loop: write(kc) -> issue(kc+1) -> sync -> compute(kc) -> sync ----
    issue(0);
    for (int kc = 0; kc < kNK; ++kc) {
        write_lds();
        if (kc < kNK - 1) issue(kc + 1);
        __syncthreads();
        bf16x8 a = *(const bf16x8*)&lds[aoff];
#pragma unroll
        for (int p = 0; p < kWin; ++p) {
            bf16x8 bb = *(const bf16x8*)&lds[boff + p * (kSX * kCP)];
            acc[p] = __builtin_amdgcn_mfma_f32_16x16x32_bf16(a, bb, acc[p], 0, 0, 0);
        }
        __syncthreads();
    }

    // ---- epilogue: band-extract into OUT_lds, then coalesced stores ----
    float* outb = (float*)lds;
    const float inv = 1.0f / (float)kC;
    const int delta = (mn & 1) ? 12 : -4;      // (Xn - Xm) + 4
#pragma unroll
    for (int p = 0; p < kWin; ++p) {
#pragma unroll
        for (int r = 0; r < 4; ++r) {
            int m = (lg << 2) + r;
            int o = l15 - m + delta;
            if (o >= 0 && o < kWin) {
                int d = p * kWin + o;
                outb[d * kOS + yslot * kXB + Ms * 16 + m] = acc[p][r] * inv;
            }
        }
    }
    __syncthreads();

    const size_t ob = (size_t)b * (kWin * kWin) * kCStr;
    for (int i = tid; i < kWin * kWin * kYB * (kXB / 4); i += kThreads) {
        int d = i >> 5;                 // 32 float4 per d (4y x 8xq)
        int r2 = i & 31;
        int yy = r2 >> 3, xq = r2 & 7;
        float4 v = *(const float4*)&outb[d * kOS + yy * kXB + xq * 4];
        *(float4*)&out[ob + ((size_t)d * kH + (y0 + yy)) * kW + X0 + xq * 4] = v;
    }
}

extern "C" void kernel_launch(void* const* d_in, const int* in_sizes, int n_in,
                              void* d_out, int out_size, void* d_ws, size_t ws_size,
                              hipStream_t stream) {
    const float* first  = (const float*)d_in[0];
    const float* second = (const float*)d_in[1];
    float* out = (float*)d_out;
    dim3 grid(kBlocks);      // 1024 blocks
    dim3 block(kThreads);    // 1024 threads = 16 waves
    hipLaunchKernelGGL(corr_mfma, grid, block, 0, stream, first, second, out);
}